// Round 9
// baseline (219.943 us; speedup 1.0000x reference)
//
#include <hip/hip_runtime.h>
#include <math.h>

static __device__ __forceinline__ float lrelu(float x){ return x > 0.f ? x : 0.01f * x; }

// ---- workspace layout (float offsets) ----
#define OFF_XE    196608    // 768*128
#define OFF_XA    294912    // 768*128
#define OFF_QKVE  393216    // 768*384
#define OFF_QKVA  688128    // 768*384
#define OFF_AOP   983040    // 4 splits * 768*128 (e partial O numerator)
#define OFF_DEN   1376256   // 4 splits * 768*4 (e partial denom)
#define OFF_AOA   1388544   // 15*96*128
#define OFF_QVE   1572864   // 768
#define OFF_QVA   1573632   // 15*96 (pad)
#define WS_FLOATS 1575072   // ~6.3 MB

// ---- output layout (fp32 elems) ----
#define OUT_POL 0
#define OUT_QV  24576
#define OUT_EO  25344

#define SCALE_ATTN 0.17677669529663689f  // 1/sqrt(32)

// ================================================================
// K12ab: front end, split into independent pipelines for occupancy.
// Blocks 0..383   (type A): row pair -> eo -> x_e -> qkv_e
// Blocks 384..767 (type B): row pair -> actor(3) -> pol -> ea -> x_a -> qkv_a
// 256 threads. All LDS operand reads are b128. grid=768 (3 blocks/CU).
// ================================================================
__global__ __launch_bounds__(256) void k12ab_front(
    const float* __restrict__ obs,
    const float* __restrict__ aw1, const float* __restrict__ ab1,
    const float* __restrict__ aw2, const float* __restrict__ ab2,
    const float* __restrict__ aw3, const float* __restrict__ ab3,
    const float* __restrict__ eow, const float* __restrict__ eob,
    const float* __restrict__ eaw, const float* __restrict__ eab,
    const float* __restrict__ riw, const float* __restrict__ rib,
    const float* __restrict__ miw, const float* __restrict__ mib,
    float* __restrict__ out, float* __restrict__ ws)
{
  __shared__ float obs_s[2][128];
  __shared__ float h256[2][256];   // B: h1
  __shared__ float bufA[2][128];   // A: eo      | B: h2
  __shared__ float bufB[2][128];   // A: xx      | B: ea
  __shared__ float bufC[2][128];   // B: xx
  __shared__ float pol[2][32];
  const int t  = threadIdx.x;
  const int bx = blockIdx.x;
  const bool isA = (bx < 384);
  const int r0 = (isA ? bx : bx - 384) * 2;

  { int r = t >> 7, k = t & 127;
    obs_s[r][k] = obs[(r0 + r) * 128 + k]; }
  __syncthreads();

  if (isA) {
    // ---------- type A: e-pipeline ----------
    const int o = t & 127, r = t >> 7;
    { // eo = obs @ eow^T + eob
      float a = eob[o];
      const float4* wr = (const float4*)(eow + o * 128);
      #pragma unroll 8
      for (int kk = 0; kk < 32; ++kk) {
        float4 w = wr[kk];
        float4 x = *(const float4*)&obs_s[r][kk * 4];
        a = fmaf(x.x, w.x, a); a = fmaf(x.y, w.y, a);
        a = fmaf(x.z, w.z, a); a = fmaf(x.w, w.w, a);
      }
      bufA[r][o] = a;
      out[OUT_EO + (r0 + r) * 128 + o] = a;
    }
    __syncthreads();
    { // x_e = relu(riw @ eo + rib)
      float a = rib[o];
      const float4* wr = (const float4*)(riw + o * 128);
      #pragma unroll 8
      for (int kk = 0; kk < 32; ++kk) {
        float4 w = wr[kk];
        float4 x = *(const float4*)&bufA[r][kk * 4];
        a = fmaf(x.x, w.x, a); a = fmaf(x.y, w.y, a);
        a = fmaf(x.z, w.z, a); a = fmaf(x.w, w.w, a);
      }
      a = fmaxf(a, 0.f);
      bufB[r][o] = a;
      ws[OFF_XE + (r0 + r) * 128 + o] = a;
    }
    __syncthreads();
    { // qkv_e = miw @ x_e + mib (3 passes of 128 outs x 2 rows)
      float* qout = ws + OFF_QKVE + (size_t)r0 * 384;
      #pragma unroll
      for (int p3 = 0; p3 < 3; ++p3) {
        const int oo = p3 * 128 + o;
        float a = mib[oo];
        const float4* wr = (const float4*)(miw + oo * 128);
        #pragma unroll 8
        for (int kk = 0; kk < 32; ++kk) {
          float4 w = wr[kk];
          float4 x = *(const float4*)&bufB[r][kk * 4];
          a = fmaf(x.x, w.x, a); a = fmaf(x.y, w.y, a);
          a = fmaf(x.z, w.z, a); a = fmaf(x.w, w.w, a);
        }
        qout[(size_t)r * 384 + oo] = a;
      }
    }
  } else {
    // ---------- type B: actor + a-pipeline ----------
    { // layer1: 256 outputs x 2 rows (ILP 2)
      const int o = t;
      float a0 = ab1[o]; float a1 = a0;
      const float4* wr = (const float4*)(aw1 + o * 128);
      #pragma unroll 8
      for (int kk = 0; kk < 32; ++kk) {
        float4 w  = wr[kk];
        float4 x0 = *(const float4*)&obs_s[0][kk * 4];
        float4 x1 = *(const float4*)&obs_s[1][kk * 4];
        a0 = fmaf(x0.x, w.x, a0); a0 = fmaf(x0.y, w.y, a0);
        a0 = fmaf(x0.z, w.z, a0); a0 = fmaf(x0.w, w.w, a0);
        a1 = fmaf(x1.x, w.x, a1); a1 = fmaf(x1.y, w.y, a1);
        a1 = fmaf(x1.z, w.z, a1); a1 = fmaf(x1.w, w.w, a1);
      }
      h256[0][o] = lrelu(a0); h256[1][o] = lrelu(a1);
    }
    __syncthreads();
    { // layer2: 128 outs x 2 rows, one (o,r) per thread, chain 256
      const int o = t & 127, r = t >> 7;
      float a = ab2[o];
      const float4* wr = (const float4*)(aw2 + o * 256);
      #pragma unroll 8
      for (int kk = 0; kk < 64; ++kk) {
        float4 w = wr[kk];
        float4 x = *(const float4*)&h256[r][kk * 4];
        a = fmaf(x.x, w.x, a); a = fmaf(x.y, w.y, a);
        a = fmaf(x.z, w.z, a); a = fmaf(x.w, w.w, a);
      }
      bufA[r][o] = lrelu(a);
    }
    __syncthreads();
    if (t < 64) { // layer3 + exact GELU -> policy
      const int o = t & 31, r = t >> 5;
      float a = ab3[o];
      const float4* wr = (const float4*)(aw3 + o * 128);
      #pragma unroll 8
      for (int kk = 0; kk < 32; ++kk) {
        float4 w = wr[kk];
        float4 x = *(const float4*)&bufA[r][kk * 4];
        a = fmaf(x.x, w.x, a); a = fmaf(x.y, w.y, a);
        a = fmaf(x.z, w.z, a); a = fmaf(x.w, w.w, a);
      }
      float g = 0.5f * a * (1.f + erff(a * 0.70710678118654752f));
      pol[r][o] = g;
      out[OUT_POL + (r0 + r) * 32 + o] = g;
    }
    __syncthreads();
    { // ea = [obs, pol] @ eaw^T + eab (one (o,r) per thread, chain 160)
      const int o = t & 127, r = t >> 7;
      float a = eab[o];
      const float4* wr = (const float4*)(eaw + o * 160);
      #pragma unroll 8
      for (int kk = 0; kk < 32; ++kk) {
        float4 w = wr[kk];
        float4 x = *(const float4*)&obs_s[r][kk * 4];
        a = fmaf(x.x, w.x, a); a = fmaf(x.y, w.y, a);
        a = fmaf(x.z, w.z, a); a = fmaf(x.w, w.w, a);
      }
      #pragma unroll
      for (int kk = 32; kk < 40; ++kk) {
        float4 w = wr[kk];
        float4 x = *(const float4*)&pol[r][kk * 4 - 128];
        a = fmaf(x.x, w.x, a); a = fmaf(x.y, w.y, a);
        a = fmaf(x.z, w.z, a); a = fmaf(x.w, w.w, a);
      }
      bufB[r][o] = a;
    }
    __syncthreads();
    { // x_a = relu(riw @ ea + rib)
      const int o = t & 127, r = t >> 7;
      float a = rib[o];
      const float4* wr = (const float4*)(riw + o * 128);
      #pragma unroll 8
      for (int kk = 0; kk < 32; ++kk) {
        float4 w = wr[kk];
        float4 x = *(const float4*)&bufB[r][kk * 4];
        a = fmaf(x.x, w.x, a); a = fmaf(x.y, w.y, a);
        a = fmaf(x.z, w.z, a); a = fmaf(x.w, w.w, a);
      }
      a = fmaxf(a, 0.f);
      bufC[r][o] = a;
      ws[OFF_XA + (r0 + r) * 128 + o] = a;
    }
    __syncthreads();
    { // qkv_a = miw @ x_a + mib
      const int o = t & 127, r = t >> 7;
      float* qout = ws + OFF_QKVA + (size_t)r0 * 384;
      #pragma unroll
      for (int p3 = 0; p3 < 3; ++p3) {
        const int oo = p3 * 128 + o;
        float a = mib[oo];
        const float4* wr = (const float4*)(miw + oo * 128);
        #pragma unroll 8
        for (int kk = 0; kk < 32; ++kk) {
          float4 w = wr[kk];
          float4 x = *(const float4*)&bufC[r][kk * 4];
          a = fmaf(x.x, w.x, a); a = fmaf(x.y, w.y, a);
          a = fmaf(x.z, w.z, a); a = fmaf(x.w, w.w, a);
        }
        qout[(size_t)r * 384 + oo] = a;
      }
    }
  }
}

// ================================================================
// K356: fused attention. Blocks 0..767: e-slice flash (l-tile, head,
// k-split); blocks 768..887: a-slices j=1..15. LDS is a union.
// ================================================================
__global__ __launch_bounds__(256) void k356_attn(float* __restrict__ ws)
{
  __shared__ __align__(16) union {
    struct { float Qs[16 * 36]; float KsT[32 * 68]; float VsT[32 * 68]; float Ss[16 * 68]; } e;
    struct { float Qb[48 * 33]; float Ka[96 * 33]; float Va[96 * 36]; float Ss[48 * 97]; float rinv[48]; } a;
  } su;
  const int t  = threadIdx.x;
  const int bx = blockIdx.x;

  if (bx < 768) {
    // ---------------- e-slice flash ----------------
    const int l0 = (bx % 48) * 16, h = (bx / 48) & 3, sp = bx / 192;
    const float* qkve = ws + OFF_QKVE;

    for (int f = t; f < 512; f += 256)
      su.e.Qs[(f >> 5) * 36 + (f & 31)] = qkve[(size_t)(l0 + (f >> 5)) * 384 + h * 32 + (f & 31)];
    __syncthreads();

    const int l = t >> 4, j = t & 15, c0 = j * 4;
    float q[32];
    #pragma unroll
    for (int dd = 0; dd < 8; ++dd) {
      float4 qq = *(const float4*)&su.e.Qs[l * 36 + dd * 4];
      q[dd*4+0] = qq.x; q[dd*4+1] = qq.y; q[dd*4+2] = qq.z; q[dd*4+3] = qq.w;
    }
    float o0 = 0.f, o1 = 0.f, dsum = 0.f;

    for (int mt = sp * 3; mt < sp * 3 + 3; ++mt) {
      const int m0 = mt * 64;
      __syncthreads();
      for (int f = t; f < 2048; f += 256) {
        int i = f >> 5, d = f & 31;
        const float* src = qkve + (size_t)(m0 + i) * 384 + h * 32 + d;
        su.e.KsT[d * 68 + i] = src[128];
        su.e.VsT[d * 68 + i] = src[256];
      }
      __syncthreads();

      float s0 = 0.f, s1 = 0.f, s2 = 0.f, s3 = 0.f;
      #pragma unroll
      for (int d = 0; d < 32; ++d) {
        float4 kk = *(const float4*)&su.e.KsT[d * 68 + c0];
        s0 = fmaf(q[d], kk.x, s0); s1 = fmaf(q[d], kk.y, s1);
        s2 = fmaf(q[d], kk.z, s2); s3 = fmaf(q[d], kk.w, s3);
      }
      s0 = expf(s0 * SCALE_ATTN); s1 = expf(s1 * SCALE_ATTN);
      s2 = expf(s2 * SCALE_ATTN); s3 = expf(s3 * SCALE_ATTN);
      float4 sv; sv.x = s0; sv.y = s1; sv.z = s2; sv.w = s3;
      *(float4*)&su.e.Ss[l * 68 + c0] = sv;
      float psum = (s0 + s1) + (s2 + s3);
      psum += __shfl_xor(psum, 1); psum += __shfl_xor(psum, 2);
      psum += __shfl_xor(psum, 4); psum += __shfl_xor(psum, 8);
      dsum += psum;

      #pragma unroll
      for (int k4 = 0; k4 < 16; ++k4) {
        float4 p  = *(const float4*)&su.e.Ss[l * 68 + k4 * 4];
        float4 va = *(const float4*)&su.e.VsT[j * 68 + k4 * 4];
        float4 vb = *(const float4*)&su.e.VsT[(j + 16) * 68 + k4 * 4];
        o0 = fmaf(p.x, va.x, o0); o0 = fmaf(p.y, va.y, o0);
        o0 = fmaf(p.z, va.z, o0); o0 = fmaf(p.w, va.w, o0);
        o1 = fmaf(p.x, vb.x, o1); o1 = fmaf(p.y, vb.y, o1);
        o1 = fmaf(p.z, vb.z, o1); o1 = fmaf(p.w, vb.w, o1);
      }
    }

    float* aop = ws + OFF_AOP + (size_t)sp * 98304;
    aop[(size_t)(l0 + l) * 128 + h * 32 + j]      = o0;
    aop[(size_t)(l0 + l) * 128 + h * 32 + j + 16] = o1;
    if (j == 0) ws[OFF_DEN + sp * 3072 + (l0 + l) * 4 + h] = dsum;
  } else {
    // ---------------- a-slices ----------------
    const int z  = bx - 768;
    const int j1 = z >> 3;
    const int h  = (z & 7) >> 1, rb = z & 1;
    const int jj = j1 + 1;
    const float* qkva = ws + OFF_QKVA;

    for (int f = t; f < 3072; f += 256) {
      int ml = f >> 5, d = f & 31;
      int bp = ml >> 1, spar = ml & 1;
      int ag = spar ? jj : (jj - 1);
      const float* src = qkva + (size_t)(bp * 16 + ag) * 384 + h * 32 + d;
      su.a.Ka[ml * 33 + d] = src[128];
      su.a.Va[ml * 36 + d] = src[256];
    }
    for (int f = t; f < 1536; f += 256) {
      int ql = f >> 5, d = f & 31;
      int Lb = rb * 48 + ql;
      int b = Lb >> 1, s = Lb & 1;
      int ag = s ? jj : (jj - 1);
      su.a.Qb[ql * 33 + d] = qkva[(size_t)(b * 16 + ag) * 384 + h * 32 + d];
    }
    __syncthreads();

    { // scores 48x96 -> weighted exp -> Ss + row sums
      const int tl = (t >> 4) * 3, tm = (t & 15) * 6;
      float acc[3][6] = {{0.f}};
      #pragma unroll
      for (int d = 0; d < 32; ++d) {
        float qv[3], kv[6];
        #pragma unroll
        for (int r = 0; r < 3; ++r) qv[r] = su.a.Qb[(tl + r) * 33 + d];
        #pragma unroll
        for (int c = 0; c < 6; ++c) kv[c] = su.a.Ka[(tm + c) * 33 + d];
        #pragma unroll
        for (int r = 0; r < 3; ++r)
          #pragma unroll
          for (int c = 0; c < 6; ++c) acc[r][c] = fmaf(qv[r], kv[c], acc[r][c]);
      }
      const float wj = (float)jj, wnj = (float)(16 - jj);
      float rs[3] = {0.f, 0.f, 0.f};
      #pragma unroll
      for (int r = 0; r < 3; ++r)
        #pragma unroll
        for (int c = 0; c < 6; ++c) {
          float w = ((tm + c) & 1) ? wj : wnj;
          float p = w * expf(acc[r][c] * SCALE_ATTN);
          su.a.Ss[(tl + r) * 97 + tm + c] = p;
          rs[r] += p;
        }
      #pragma unroll
      for (int r = 0; r < 3; ++r) {
        rs[r] += __shfl_xor(rs[r], 1); rs[r] += __shfl_xor(rs[r], 2);
        rs[r] += __shfl_xor(rs[r], 4); rs[r] += __shfl_xor(rs[r], 8);
      }
      if ((t & 15) == 0) {
        su.a.rinv[tl + 0] = 1.f / rs[0];
        su.a.rinv[tl + 1] = 1.f / rs[1];
        su.a.rinv[tl + 2] = 1.f / rs[2];
      }
    }
    __syncthreads();

    if (t < 192) { // P@V
      const int l0 = (t >> 3) * 2, d0 = (t & 7) * 4;
      float a0x=0.f,a0y=0.f,a0z=0.f,a0w=0.f, a1x=0.f,a1y=0.f,a1z=0.f,a1w=0.f;
      for (int m = 0; m < 96; ++m) {
        float p0 = su.a.Ss[l0 * 97 + m], p1 = su.a.Ss[(l0 + 1) * 97 + m];
        float4 v = *(const float4*)&su.a.Va[m * 36 + d0];
        a0x = fmaf(p0, v.x, a0x); a0y = fmaf(p0, v.y, a0y);
        a0z = fmaf(p0, v.z, a0z); a0w = fmaf(p0, v.w, a0w);
        a1x = fmaf(p1, v.x, a1x); a1y = fmaf(p1, v.y, a1y);
        a1z = fmaf(p1, v.z, a1z); a1w = fmaf(p1, v.w, a1w);
      }
      const float s0 = su.a.rinv[l0], s1 = su.a.rinv[l0 + 1];
      float* ao = ws + OFF_AOA + (size_t)(j1 * 96 + rb * 48 + l0) * 128 + h * 32 + d0;
      float4 o0; o0.x = a0x * s0; o0.y = a0y * s0; o0.z = a0z * s0; o0.w = a0w * s0;
      float4 o1; o1.x = a1x * s1; o1.y = a1y * s1; o1.z = a1z * s1; o1.w = a1w * s1;
      *(float4*)ao = o0;
      *(float4*)(ao + 128) = o1;
    }
  }
}

// ================================================================
// K7: epilogue, 2 ctx rows per 128-thread block. grid=1104.
// ================================================================
__global__ __launch_bounds__(128) void k7_epilogue(
    const float* __restrict__ mow, const float* __restrict__ mob,
    const float* __restrict__ roww, const float* __restrict__ robb,
    const float* __restrict__ qw,  const float* __restrict__ qb,
    float* __restrict__ ws)
{
  __shared__ float ao_s[2][128];
  __shared__ float t1[2][128];
  __shared__ float red2[2][2];
  const int t  = threadIdx.x;
  const int bx = blockIdx.x;
  const bool is_e = (bx < 384);
  const int r0 = is_e ? bx * 2 : (bx - 384) * 2;

  int x1off[2];
  if (is_e) {
    for (int f = t; f < 256; f += 128) {
      int i = f >> 7, c = f & 127;
      int r = r0 + i, h = c >> 5;
      float num = ws[OFF_AOP + 0*98304 + (size_t)r*128 + c]
                + ws[OFF_AOP + 1*98304 + (size_t)r*128 + c]
                + ws[OFF_AOP + 2*98304 + (size_t)r*128 + c]
                + ws[OFF_AOP + 3*98304 + (size_t)r*128 + c];
      float den = ws[OFF_DEN + 0*3072 + r*4 + h]
                + ws[OFF_DEN + 1*3072 + r*4 + h]
                + ws[OFF_DEN + 2*3072 + r*4 + h]
                + ws[OFF_DEN + 3*3072 + r*4 + h];
      ao_s[i][c] = num / den;
    }
    x1off[0] = OFF_XE + r0 * 128;
    x1off[1] = OFF_XE + (r0 + 1) * 128;
  } else {
    for (int f = t; f < 256; f += 128) {
      int i = f >> 7, c = f & 127;
      ao_s[i][c] = ws[OFF_AOA + (size_t)(r0 + i) * 128 + c];
    }
    #pragma unroll
    for (int i = 0; i < 2; ++i) {
      int rr = r0 + i;
      int jx = rr / 96, l96 = rr % 96;
      int b = l96 >> 1, s = l96 & 1;
      int ag = s ? (jx + 1) : jx;
      x1off[i] = OFF_XA + (b * 16 + ag) * 128;
    }
  }
  __syncthreads();

  { // out_proj + residual
    const int o = t;
    const float bo = mob[o];
    float acc0 = bo, acc1 = bo;
    const float4* wr = (const float4*)(mow + o * 128);
    #pragma unroll 8
    for (int kk = 0; kk < 32; ++kk) {
      float4 w  = wr[kk];
      float4 x0 = *(const float4*)&ao_s[0][kk * 4];
      float4 x1 = *(const float4*)&ao_s[1][kk * 4];
      acc0 = fmaf(x0.x, w.x, acc0); acc0 = fmaf(x0.y, w.y, acc0);
      acc0 = fmaf(x0.z, w.z, acc0); acc0 = fmaf(x0.w, w.w, acc0);
      acc1 = fmaf(x1.x, w.x, acc1); acc1 = fmaf(x1.y, w.y, acc1);
      acc1 = fmaf(x1.z, w.z, acc1); acc1 = fmaf(x1.w, w.w, acc1);
    }
    t1[0][o] = acc0 + ws[x1off[0] + o];
    t1[1][o] = acc1 + ws[x1off[1] + o];
  }
  __syncthreads();

  float c0, c1;
  { // ctx = relu(row @ t1 + rob)
    const int o = t;
    const float bo = robb[o];
    float acc0 = bo, acc1 = bo;
    const float4* wr = (const float4*)(roww + o * 128);
    #pragma unroll 8
    for (int kk = 0; kk < 32; ++kk) {
      float4 w  = wr[kk];
      float4 x0 = *(const float4*)&t1[0][kk * 4];
      float4 x1 = *(const float4*)&t1[1][kk * 4];
      acc0 = fmaf(x0.x, w.x, acc0); acc0 = fmaf(x0.y, w.y, acc0);
      acc0 = fmaf(x0.z, w.z, acc0); acc0 = fmaf(x0.w, w.w, acc0);
      acc1 = fmaf(x1.x, w.x, acc1); acc1 = fmaf(x1.y, w.y, acc1);
      acc1 = fmaf(x1.z, w.z, acc1); acc1 = fmaf(x1.w, w.w, acc1);
    }
    c0 = fmaxf(acc0, 0.f); c1 = fmaxf(acc1, 0.f);
  }

  const float qwt = qw[t];
  {
    float v = qwt * c0;
    v += __shfl_down(v, 32); v += __shfl_down(v, 16); v += __shfl_down(v, 8);
    v += __shfl_down(v, 4);  v += __shfl_down(v, 2);  v += __shfl_down(v, 1);
    if ((t & 63) == 0) red2[0][t >> 6] = v;
    float u = qwt * c1;
    u += __shfl_down(u, 32); u += __shfl_down(u, 16); u += __shfl_down(u, 8);
    u += __shfl_down(u, 4);  u += __shfl_down(u, 2);  u += __shfl_down(u, 1);
    if ((t & 63) == 0) red2[1][t >> 6] = u;
  }
  __syncthreads();
  if (t < 2) {
    float qv = red2[t][0] + red2[t][1] + qb[0];
    int r = r0 + t;
    if (is_e) ws[OFF_QVE + r] = qv;
    else      ws[OFF_QVA + r] = qv;
  }
}

// ================================================================
// K8: q_values[b,i] = qv_e[b,i] + sum_j qv_a
// ================================================================
__global__ __launch_bounds__(256) void k8_final(const float* __restrict__ ws, float* __restrict__ out)
{
  const int idx = blockIdx.x * 256 + threadIdx.x;
  if (idx >= 768) return;
  const int b = idx >> 4, i = idx & 15;
  float acc = ws[OFF_QVE + idx];
  const float* qva = ws + OFF_QVA;
  #pragma unroll
  for (int j = 1; j <= 15; ++j) {
    int s = (i >= j) ? 0 : 1;
    acc += qva[(j - 1) * 96 + b * 2 + s];
  }
  out[OUT_QV + idx] = acc;
}

// ================================================================
extern "C" void kernel_launch(void* const* d_in, const int* in_sizes, int n_in,
                              void* d_out, int out_size, void* d_ws, size_t ws_size,
                              hipStream_t stream)
{
  (void)in_sizes; (void)n_in; (void)out_size;
  if (ws_size < (size_t)WS_FLOATS * 4) return;

  const float* obs = (const float*)d_in[0];
  const float* aw1 = (const float*)d_in[1];
  const float* ab1 = (const float*)d_in[2];
  const float* aw2 = (const float*)d_in[3];
  const float* ab2 = (const float*)d_in[4];
  const float* aw3 = (const float*)d_in[5];
  const float* ab3 = (const float*)d_in[6];
  const float* eow = (const float*)d_in[7];
  const float* eob = (const float*)d_in[8];
  const float* eaw = (const float*)d_in[9];
  const float* eab = (const float*)d_in[10];
  const float* riw = (const float*)d_in[11];
  const float* rib = (const float*)d_in[12];
  const float* roww= (const float*)d_in[13];
  const float* robb= (const float*)d_in[14];
  const float* miw = (const float*)d_in[15];
  const float* mib = (const float*)d_in[16];
  const float* mow = (const float*)d_in[17];
  const float* mob = (const float*)d_in[18];
  const float* qw  = (const float*)d_in[19];
  const float* qb  = (const float*)d_in[20];

  float* out = (float*)d_out;
  float* ws  = (float*)d_ws;

  k12ab_front<<<dim3(768), dim3(256), 0, stream>>>(obs, aw1, ab1, aw2, ab2, aw3, ab3,
                                                   eow, eob, eaw, eab, riw, rib, miw, mib,
                                                   out, ws);
  k356_attn<<<dim3(888), dim3(256), 0, stream>>>(ws);
  k7_epilogue<<<dim3(1104), dim3(128), 0, stream>>>(mow, mob, roww, robb, qw, qb, ws);
  k8_final<<<dim3(3), dim3(256), 0, stream>>>(ws, out);
}